// Round 5
// baseline (817.441 us; speedup 1.0000x reference)
//
#include <hip/hip_runtime.h>
#include <math.h>

#define HSZ 50000
#define INSZ 50000
#define NNZc 800000
#define BSZ 8
#define TSZ 32
#define NCHUNK 49                 // ceil(HSZ/1024)
#define KROWS 32                  // rows per bucket
#define NBUCKET ((HSZ + KROWS - 1) / KROWS)   // 1563

typedef _Float16 half8 __attribute__((ext_vector_type(8)));
typedef _Float16 half4 __attribute__((ext_vector_type(4)));

__device__ __forceinline__ unsigned f2h_bits(float f) {
    _Float16 h = (_Float16)f;
    unsigned short u;
    __builtin_memcpy(&u, &h, 2);
    return (unsigned)u;
}
__device__ __forceinline__ float h_bits2f(unsigned u) {
    unsigned short us = (unsigned short)u;
    _Float16 h;
    __builtin_memcpy(&h, &us, 2);
    return (float)h;
}

// ---------------- CSR build ----------------

__global__ void hist_kernel(const int* __restrict__ hh_idx, const int* __restrict__ ih_idx,
                            int* __restrict__ hh_cnt, int* __restrict__ ih_cnt) {
    int i = blockIdx.x * blockDim.x + threadIdx.x;
    if (i < NNZc) {
        atomicAdd(&hh_cnt[hh_idx[i]], 1);
    } else if (i < 2 * NNZc) {
        atomicAdd(&ih_cnt[ih_idx[i - NNZc]], 1);
    }
}

__global__ void scanA_kernel(const int* __restrict__ cnt_hh, const int* __restrict__ cnt_ih,
                             int* __restrict__ ptr_hh, int* __restrict__ ptr_ih,
                             int* __restrict__ partials) {
    const int* cnt = blockIdx.y ? cnt_ih : cnt_hh;
    int* ptr = blockIdx.y ? ptr_ih : ptr_hh;
    __shared__ int sm[1024];
    int tid = threadIdx.x;
    int idx = blockIdx.x * 1024 + tid;
    int v = (idx < HSZ) ? cnt[idx] : 0;
    sm[tid] = v;
    __syncthreads();
    int x = v;
    for (int off = 1; off < 1024; off <<= 1) {
        int y = (tid >= off) ? sm[tid - off] : 0;
        __syncthreads();
        x += y;
        sm[tid] = x;
        __syncthreads();
    }
    if (idx < HSZ) ptr[idx] = x - v;
    if (tid == 1023) partials[blockIdx.y * 64 + blockIdx.x] = x;
}

__global__ void scanB_kernel(int* __restrict__ partials) {
    int lane = threadIdx.x;
    for (int m = 0; m < 2; ++m) {
        int v = (lane < NCHUNK) ? partials[m * 64 + lane] : 0;
        int orig = v;
        for (int off = 1; off < 64; off <<= 1) {
            int y = __shfl_up(v, off, 64);
            if (lane >= off) v += y;
        }
        if (lane < NCHUNK) partials[m * 64 + lane] = v - orig;
    }
}

// finalizes ptr and seeds the bucket append cursors bfill[bkt] = ptr[bkt*KROWS]
__global__ void scanC_kernel(int* __restrict__ ptr_hh, int* __restrict__ ptr_ih,
                             int* __restrict__ bfill_hh, int* __restrict__ bfill_ih,
                             const int* __restrict__ partials) {
    int mat = blockIdx.y;
    int* ptr   = mat ? ptr_ih : ptr_hh;
    int* bfill = mat ? bfill_ih : bfill_hh;
    int i = blockIdx.x * 256 + threadIdx.x;
    if (i < HSZ) {
        int v = ptr[i] + partials[mat * 64 + (i >> 10)];
        ptr[i] = v;
        if ((i & (KROWS - 1)) == 0) bfill[i / KROWS] = v;
    }
    if (i == 0) ptr[HSZ] = NNZc;
}

// Phase 1: append nnz into its bucket region (frontier lines stay hot in L2).
__global__ void bucket_append(const int* __restrict__ hh_idx, const float* __restrict__ hh_v,
                              const int* __restrict__ ih_idx, const float* __restrict__ ih_v,
                              int* __restrict__ bfill_hh, int* __restrict__ bfill_ih,
                              uint2* __restrict__ tmp_hh, uint2* __restrict__ tmp_ih) {
    int i = blockIdx.x * blockDim.x + threadIdx.x;
    if (i < NNZc) {
        int r = hh_idx[i];
        int c = hh_idx[NNZc + i];
        int pos = atomicAdd(&bfill_hh[r >> 5], 1);
        tmp_hh[pos] = make_uint2(((unsigned)(r & 31) << 16) | (unsigned)c,
                                 __float_as_uint(hh_v[i]));
    } else if (i < 2 * NNZc) {
        int k = i - NNZc;
        int r = ih_idx[k];
        int c = ih_idx[NNZc + k];
        int pos = atomicAdd(&bfill_ih[r >> 5], 1);
        tmp_ih[pos] = make_uint2(((unsigned)(r & 31) << 16) | (unsigned)c,
                                 __float_as_uint(ih_v[k]));
    }
}

// Phase 2: one block per bucket; place elements at exact CSR positions via LDS
// counters. Final cv entry: 4 bytes = (half(val) << 16) | col.
__global__ void bucket_finalize(const int* __restrict__ ptr_hh, const int* __restrict__ ptr_ih,
                                const uint2* __restrict__ tmp_hh, const uint2* __restrict__ tmp_ih,
                                unsigned* __restrict__ cv_hh, unsigned* __restrict__ cv_ih) {
    int mat = blockIdx.y;
    const int* ptr   = mat ? ptr_ih : ptr_hh;
    const uint2* tmp = mat ? tmp_ih : tmp_hh;
    unsigned* cv     = mat ? cv_ih : cv_hh;
    __shared__ int fill[KROWS];
    int bkt = blockIdx.x;
    int row0 = bkt * KROWS;
    int rows = min(KROWS, HSZ - row0);
    int tid = threadIdx.x;
    if (tid < rows) fill[tid] = ptr[row0 + tid];
    __syncthreads();
    int s = ptr[row0];
    int e = ptr[row0 + rows];
    for (int k = s + tid; k < e; k += 256) {
        uint2 el = tmp[k];
        int lr = (int)(el.x >> 16);
        unsigned c = el.x & 0xffffu;
        int pos = atomicAdd(&fill[lr], 1);
        cv[pos] = (f2h_bits(__uint_as_float(el.y)) << 16) | c;
    }
}

// ---------------- transpose: x (B,T,IN) -> X2h (IN, 256) fp16, col = t*8+b ----------------

__global__ void transpose_x2(const float* __restrict__ x, _Float16* __restrict__ X2h) {
    extern __shared__ float tile[];   // 64 * 257 floats
    int i0 = blockIdx.x * 64;
    int tid = threadIdx.x;
    int il = tid & 63, tg = tid >> 6;
    for (int k = 0; k < 64; ++k) {
        int tb = k * 4 + tg;                 // 0..255
        int t = tb >> 3, b = tb & 7;
        int i = i0 + il;
        float v = (i < INSZ) ? x[((size_t)b * TSZ + t) * INSZ + i] : 0.f;
        tile[il * 257 + tb] = v;             // stride 257: conflict-free
    }
    __syncthreads();
    for (int k = 0; k < 64; ++k) {
        int i = i0 + k;
        if (i < INSZ) X2h[(size_t)i * 256 + tid] = (_Float16)tile[k * 257 + tid];
    }
}

// ---------------- ihc: one wave per row; output in t-major layout ----------------
// lane = t*2+q holds half4 for (t, b=q*4..q*4+3). LDS transpose so each block of
// 4 rows writes one FULL 64B line per t-plane: ihcT half4 index (t*HSZ + r)*2 + q.

__global__ void ihc_kernel(const int* __restrict__ ptr, const unsigned* __restrict__ cv,
                           const float* __restrict__ bias, const half4* __restrict__ X2h,
                           half4* __restrict__ ihcT) {
    __shared__ half4 lds[4 * 65];
    int wid = threadIdx.x >> 6;
    int lane = threadIdx.x & 63;
    int r = (blockIdx.x << 2) + wid;          // HSZ % 4 == 0: always valid
    int s = ptr[r], e = ptr[r + 1];
    s = __builtin_amdgcn_readfirstlane(s);
    e = __builtin_amdgcn_readfirstlane(e);
    float4 acc = make_float4(0.f, 0.f, 0.f, 0.f);
    int j = s;
    for (; j + 1 < e; j += 2) {
        unsigned a = cv[j], b = cv[j + 1];
        float va = h_bits2f(a >> 16);
        float vb = h_bits2f(b >> 16);
        half4 x0 = X2h[((size_t)(a & 0xffffu) << 6) + lane];
        half4 x1 = X2h[((size_t)(b & 0xffffu) << 6) + lane];
        acc.x = fmaf(va, (float)x0[0], acc.x);
        acc.y = fmaf(va, (float)x0[1], acc.y);
        acc.z = fmaf(va, (float)x0[2], acc.z);
        acc.w = fmaf(va, (float)x0[3], acc.w);
        acc.x = fmaf(vb, (float)x1[0], acc.x);
        acc.y = fmaf(vb, (float)x1[1], acc.y);
        acc.z = fmaf(vb, (float)x1[2], acc.z);
        acc.w = fmaf(vb, (float)x1[3], acc.w);
    }
    if (j < e) {
        unsigned a = cv[j];
        float va = h_bits2f(a >> 16);
        half4 x0 = X2h[((size_t)(a & 0xffffu) << 6) + lane];
        acc.x = fmaf(va, (float)x0[0], acc.x);
        acc.y = fmaf(va, (float)x0[1], acc.y);
        acc.z = fmaf(va, (float)x0[2], acc.z);
        acc.w = fmaf(va, (float)x0[3], acc.w);
    }
    float bb = bias[r];
    half4 o;
    o[0] = (_Float16)(acc.x + bb);
    o[1] = (_Float16)(acc.y + bb);
    o[2] = (_Float16)(acc.z + bb);
    o[3] = (_Float16)(acc.w + bb);
    lds[wid * 65 + lane] = o;
    __syncthreads();
    // 256 threads = 32 planes x (4 rows x 2 q): one 64B line per plane
    int plane = threadIdx.x >> 3;
    int w = threadIdx.x & 7;
    int row = w >> 1, q = w & 1;
    int r2 = (blockIdx.x << 2) + row;
    ihcT[((size_t)plane * HSZ + r2) * 2 + q] = lds[row * 65 + 2 * plane + q];
}

// ---------------- recurrence step ----------------

__device__ __forceinline__ float fast_tanh(float x) {
    float e = __expf(2.0f * x);
    return 1.0f - __fdividef(2.0f, e + 1.0f);
}

__global__ void step_kernel(const int* __restrict__ ptr, const unsigned* __restrict__ cv,
                            const half8* __restrict__ ihcT, const half8* __restrict__ h_in,
                            half8* __restrict__ h_out, float* __restrict__ out, int t) {
    int gid = blockIdx.x * 256 + threadIdx.x;    // gid = r*4 + sub
    if (gid >= 4 * HSZ) return;
    int sub = gid & 3;
    int r = gid >> 2;
    int s = ptr[r], e = ptr[r + 1];
    half8 base8 = ihcT[(size_t)t * HSZ + r];     // contiguous 800KB stream per step
    float acc0 = 0.f, acc1 = 0.f, acc2 = 0.f, acc3 = 0.f;
    float acc4 = 0.f, acc5 = 0.f, acc6 = 0.f, acc7 = 0.f;
    for (int j = s + sub; j < e; j += 4) {
        unsigned u = cv[j];                      // 4 lanes: 16B coalesced
        float v = h_bits2f(u >> 16);
        half8 hv = h_in[u & 0xffffu];
        acc0 = fmaf(v, (float)hv[0], acc0);
        acc1 = fmaf(v, (float)hv[1], acc1);
        acc2 = fmaf(v, (float)hv[2], acc2);
        acc3 = fmaf(v, (float)hv[3], acc3);
        acc4 = fmaf(v, (float)hv[4], acc4);
        acc5 = fmaf(v, (float)hv[5], acc5);
        acc6 = fmaf(v, (float)hv[6], acc6);
        acc7 = fmaf(v, (float)hv[7], acc7);
    }
    acc0 += __shfl_xor(acc0, 1); acc1 += __shfl_xor(acc1, 1);
    acc2 += __shfl_xor(acc2, 1); acc3 += __shfl_xor(acc3, 1);
    acc4 += __shfl_xor(acc4, 1); acc5 += __shfl_xor(acc5, 1);
    acc6 += __shfl_xor(acc6, 1); acc7 += __shfl_xor(acc7, 1);
    acc0 += __shfl_xor(acc0, 2); acc1 += __shfl_xor(acc1, 2);
    acc2 += __shfl_xor(acc2, 2); acc3 += __shfl_xor(acc3, 2);
    acc4 += __shfl_xor(acc4, 2); acc5 += __shfl_xor(acc5, 2);
    acc6 += __shfl_xor(acc6, 2); acc7 += __shfl_xor(acc7, 2);
    if (sub == 0) {
        float h0 = fast_tanh(acc0 + (float)base8[0]);
        float h1 = fast_tanh(acc1 + (float)base8[1]);
        float h2 = fast_tanh(acc2 + (float)base8[2]);
        float h3 = fast_tanh(acc3 + (float)base8[3]);
        float h4 = fast_tanh(acc4 + (float)base8[4]);
        float h5 = fast_tanh(acc5 + (float)base8[5]);
        float h6 = fast_tanh(acc6 + (float)base8[6]);
        float h7 = fast_tanh(acc7 + (float)base8[7]);
        half8 hh;
        hh[0] = (_Float16)h0; hh[1] = (_Float16)h1;
        hh[2] = (_Float16)h2; hh[3] = (_Float16)h3;
        hh[4] = (_Float16)h4; hh[5] = (_Float16)h5;
        hh[6] = (_Float16)h6; hh[7] = (_Float16)h7;
        h_out[r] = hh;
        out[((size_t)0 * TSZ + t) * HSZ + r] = h0;
        out[((size_t)1 * TSZ + t) * HSZ + r] = h1;
        out[((size_t)2 * TSZ + t) * HSZ + r] = h2;
        out[((size_t)3 * TSZ + t) * HSZ + r] = h3;
        out[((size_t)4 * TSZ + t) * HSZ + r] = h4;
        out[((size_t)5 * TSZ + t) * HSZ + r] = h5;
        out[((size_t)6 * TSZ + t) * HSZ + r] = h6;
        out[((size_t)7 * TSZ + t) * HSZ + r] = h7;
    }
}

// ---------------- launch ----------------

static inline size_t align256(size_t x) { return (x + 255) & ~(size_t)255; }

extern "C" void kernel_launch(void* const* d_in, const int* in_sizes, int n_in,
                              void* d_out, int out_size, void* d_ws, size_t ws_size,
                              hipStream_t stream) {
    const float* x          = (const float*)d_in[0];
    const float* hh_values  = (const float*)d_in[1];
    const float* hh_bias    = (const float*)d_in[2];
    const float* ih_values  = (const float*)d_in[3];
    const int*   hh_indices = (const int*)d_in[4];
    const int*   ih_indices = (const int*)d_in[5];
    float* out = (float*)d_out;

    char* ws = (char*)d_ws;
    _Float16* X2h   = (_Float16*)ws; ws += align256((size_t)INSZ * 256 * 2);   // 25.6 MB
    half4*  ihcT    = (half4*)ws;  ws += align256((size_t)HSZ * 256 * 2);      // 25.6 MB
    half8*  hbuf    = (half8*)ws;  ws += align256((size_t)2 * HSZ * 16);       // 1.6 MB
    int*    hh_ptr  = (int*)ws;    ws += align256((size_t)(HSZ + 1) * 4);
    int*    hh_cnt  = (int*)ws;    ws += align256((size_t)HSZ * 4);
    int*    ih_ptr  = (int*)ws;    ws += align256((size_t)(HSZ + 1) * 4);
    int*    ih_cnt  = (int*)ws;    ws += align256((size_t)HSZ * 4);
    int*    bfill_hh= (int*)ws;    ws += align256((size_t)NBUCKET * 4);
    int*    bfill_ih= (int*)ws;    ws += align256((size_t)NBUCKET * 4);
    uint2*  tmp_hh  = (uint2*)ws;  ws += align256((size_t)NNZc * 8);           // 6.4 MB
    uint2*  tmp_ih  = (uint2*)ws;  ws += align256((size_t)NNZc * 8);           // 6.4 MB
    unsigned* cv_hh = (unsigned*)ws; ws += align256((size_t)NNZc * 4);         // 3.2 MB
    unsigned* cv_ih = (unsigned*)ws; ws += align256((size_t)NNZc * 4);         // 3.2 MB
    int*    partials= (int*)ws;    ws += align256((size_t)128 * 4);

    hipMemsetAsync(hh_cnt, 0, (size_t)HSZ * 4, stream);
    hipMemsetAsync(ih_cnt, 0, (size_t)HSZ * 4, stream);
    hipMemsetAsync(hbuf, 0, (size_t)HSZ * 16, stream);   // h0 = 0

    int histBlocks = (2 * NNZc + 255) / 256;
    hist_kernel<<<histBlocks, 256, 0, stream>>>(hh_indices, ih_indices, hh_cnt, ih_cnt);
    scanA_kernel<<<dim3(NCHUNK, 2), 1024, 0, stream>>>(hh_cnt, ih_cnt, hh_ptr, ih_ptr, partials);
    scanB_kernel<<<1, 64, 0, stream>>>(partials);
    scanC_kernel<<<dim3((HSZ + 255) / 256, 2), 256, 0, stream>>>(hh_ptr, ih_ptr, bfill_hh, bfill_ih, partials);
    bucket_append<<<histBlocks, 256, 0, stream>>>(hh_indices, hh_values, ih_indices, ih_values,
                                                  bfill_hh, bfill_ih, tmp_hh, tmp_ih);
    bucket_finalize<<<dim3(NBUCKET, 2), 256, 0, stream>>>(hh_ptr, ih_ptr, tmp_hh, tmp_ih,
                                                          cv_hh, cv_ih);

    transpose_x2<<<(INSZ + 63) / 64, 256, 64 * 257 * 4, stream>>>(x, X2h);
    ihc_kernel<<<HSZ / 4, 256, 0, stream>>>(ih_ptr, cv_ih, hh_bias, (const half4*)X2h, ihcT);

    int stepBlocks = (4 * HSZ + 255) / 256;
    for (int t = 0; t < TSZ; ++t) {
        half8* hin  = hbuf + (size_t)(t & 1) * HSZ;
        half8* hout = hbuf + (size_t)((t + 1) & 1) * HSZ;
        step_kernel<<<stepBlocks, 256, 0, stream>>>(hh_ptr, cv_hh, (const half8*)ihcT,
                                                    hin, hout, out, t);
    }
}

// Round 6
// 549.850 us; speedup vs baseline: 1.4867x; 1.4867x over previous
//
#include <hip/hip_runtime.h>
#include <math.h>

#define HSZ 50000
#define INSZ 50000
#define NNZc 800000
#define BSZ 8
#define TSZ 32

#define CHUNK 2048
#define NBLK ((NNZc + CHUNK - 1) / CHUNK)    // 391
#define NCB 196                              // ceil(HSZ/256)
#define HWORDS (256 * NBLK)                  // 100096 per matrix
#define NC2 ((HWORDS + 1023) / 1024)         // 98

typedef _Float16 half8 __attribute__((ext_vector_type(8)));
typedef _Float16 half4 __attribute__((ext_vector_type(4)));

__device__ __forceinline__ unsigned f2h_bits(float f) {
    _Float16 h = (_Float16)f;
    unsigned short u;
    __builtin_memcpy(&u, &h, 2);
    return (unsigned)u;
}
__device__ __forceinline__ float h_bits2f(unsigned u) {
    unsigned short us = (unsigned short)u;
    _Float16 h;
    __builtin_memcpy(&h, &us, 2);
    return (float)h;
}

// ---------------- CSR build: atomic-free radix partition on row>>8 ----------------

// P1: per-block LDS histogram -> ghist[mat][bucket][blk]
__global__ void p1_count(const int* __restrict__ hh_idx, const int* __restrict__ ih_idx,
                         int* __restrict__ ghist) {
    const int* rows = blockIdx.y ? ih_idx : hh_idx;
    __shared__ int cnt[256];
    int tid = threadIdx.x;
    cnt[tid] = 0;
    __syncthreads();
    int base = blockIdx.x * CHUNK;
    int nElem = min(CHUNK, NNZc - base);
    for (int k = tid; k < nElem; k += 256) {
        atomicAdd(&cnt[rows[base + k] >> 8], 1);
    }
    __syncthreads();
    ghist[((size_t)blockIdx.y * 256 + tid) * NBLK + blockIdx.x] = cnt[tid];
}

// Scan the flat [HWORDS] histogram per matrix (bucket-major => global offsets).
__global__ void p2scanA(int* __restrict__ ghist, int* __restrict__ partials) {
    int* g = ghist + (size_t)blockIdx.y * HWORDS;
    __shared__ int sm[1024];
    int tid = threadIdx.x;
    int idx = blockIdx.x * 1024 + tid;
    int v = (idx < HWORDS) ? g[idx] : 0;
    sm[tid] = v;
    __syncthreads();
    int x = v;
    for (int off = 1; off < 1024; off <<= 1) {
        int y = (tid >= off) ? sm[tid - off] : 0;
        __syncthreads();
        x += y;
        sm[tid] = x;
        __syncthreads();
    }
    if (idx < HWORDS) g[idx] = x - v;
    if (tid == 1023) partials[blockIdx.y * 128 + blockIdx.x] = x;
}

__global__ void p2scanB(int* __restrict__ partials) {
    __shared__ int sm[128];
    int tid = threadIdx.x;
    for (int m = 0; m < 2; ++m) {
        int v = (tid < NC2) ? partials[m * 128 + tid] : 0;
        sm[tid] = v;
        __syncthreads();
        int x = v;
        for (int off = 1; off < 128; off <<= 1) {
            int y = (tid >= off) ? sm[tid - off] : 0;
            __syncthreads();
            x += y;
            sm[tid] = x;
            __syncthreads();
        }
        if (tid < NC2) partials[m * 128 + tid] = x - v;
        __syncthreads();
    }
}

__global__ void p2scanC(int* __restrict__ ghist, const int* __restrict__ partials,
                        int* __restrict__ cbs) {
    int mat = blockIdx.y;
    int* g = ghist + (size_t)mat * HWORDS;
    int i = blockIdx.x * 256 + threadIdx.x;
    if (i < HWORDS) {
        int v = g[i] + partials[mat * 128 + (i >> 10)];
        g[i] = v;
        int b = i / NBLK;
        if (i - b * NBLK == 0 && b < NCB) cbs[mat * (NCB + 1) + b] = v;
    }
    if (i == 0) cbs[mat * (NCB + 1) + NCB] = NNZc;
}

// P2: block-local counting sort in LDS, then coalesced run-writes to exact offsets.
// tmp entry: x = (row<<16)|col, y = val bits.
__global__ void p2_part(const int* __restrict__ hh_idx, const float* __restrict__ hh_v,
                        const int* __restrict__ ih_idx, const float* __restrict__ ih_v,
                        const int* __restrict__ ghist,
                        uint2* __restrict__ tmp_hh, uint2* __restrict__ tmp_ih) {
    int mat = blockIdx.y;
    const int* idx = mat ? ih_idx : hh_idx;
    const float* val = mat ? ih_v : hh_v;
    uint2* tmp = mat ? tmp_ih : tmp_hh;
    const int* g = ghist + (size_t)mat * HWORDS;

    __shared__ int cnt[256];
    __shared__ int lstart[256];
    __shared__ int scanbuf[256];
    __shared__ int gbase[256];
    __shared__ uint2 stage[CHUNK];

    int tid = threadIdx.x;
    int base = blockIdx.x * CHUNK;
    int nElem = min(CHUNK, NNZc - base);

    cnt[tid] = 0;
    gbase[tid] = g[(size_t)tid * NBLK + blockIdx.x];
    __syncthreads();
    for (int k = tid; k < nElem; k += 256) {
        atomicAdd(&cnt[idx[base + k] >> 8], 1);
    }
    __syncthreads();
    // exclusive scan cnt -> lstart
    int v = cnt[tid];
    scanbuf[tid] = v;
    __syncthreads();
    int x = v;
    for (int off = 1; off < 256; off <<= 1) {
        int y = (tid >= off) ? scanbuf[tid - off] : 0;
        __syncthreads();
        x += y;
        scanbuf[tid] = x;
        __syncthreads();
    }
    lstart[tid] = x - v;
    cnt[tid] = 0;
    __syncthreads();
    // place into LDS stage at local sorted position
    for (int k = tid; k < nElem; k += 256) {
        int r = idx[base + k];
        int c = idx[NNZc + base + k];
        int b = r >> 8;
        int rank = atomicAdd(&cnt[b], 1);
        stage[lstart[b] + rank] = make_uint2(((unsigned)r << 16) | (unsigned)c,
                                             __float_as_uint(val[base + k]));
    }
    __syncthreads();
    // write runs: consecutive k within a bucket -> consecutive global dst
    for (int k = tid; k < nElem; k += 256) {
        uint2 el = stage[k];
        int b = el.x >> 24;
        tmp[gbase[b] + (k - lstart[b])] = el;
    }
}

// P3: one block per coarse bucket: build ptr (LDS scan) + exact CSR placement.
// cv entry: (half(val)<<16) | col.
__global__ void p3_final(const int* __restrict__ cbs,
                         const uint2* __restrict__ tmp_hh, const uint2* __restrict__ tmp_ih,
                         int* __restrict__ ptr_hh, int* __restrict__ ptr_ih,
                         unsigned* __restrict__ cv_hh, unsigned* __restrict__ cv_ih) {
    int mat = blockIdx.y;
    const uint2* tmp = mat ? tmp_ih : tmp_hh;
    int* ptr = mat ? ptr_ih : ptr_hh;
    unsigned* cv = mat ? cv_ih : cv_hh;
    __shared__ int rcnt[256];
    __shared__ int rstart[256];
    __shared__ int scanbuf[256];
    int cb = blockIdx.x;
    int row0 = cb << 8;
    int nrows = min(256, HSZ - row0);
    int s = cbs[mat * (NCB + 1) + cb];
    int e = cbs[mat * (NCB + 1) + cb + 1];
    int tid = threadIdx.x;
    rcnt[tid] = 0;
    __syncthreads();
    for (int k = s + tid; k < e; k += 256) {
        atomicAdd(&rcnt[(tmp[k].x >> 16) & 255], 1);
    }
    __syncthreads();
    int v = rcnt[tid];
    scanbuf[tid] = v;
    __syncthreads();
    int x = v;
    for (int off = 1; off < 256; off <<= 1) {
        int y = (tid >= off) ? scanbuf[tid - off] : 0;
        __syncthreads();
        x += y;
        scanbuf[tid] = x;
        __syncthreads();
    }
    rstart[tid] = x - v;
    if (tid < nrows) ptr[row0 + tid] = s + x - v;
    if (cb == NCB - 1 && tid == 0) ptr[HSZ] = NNZc;
    rcnt[tid] = 0;
    __syncthreads();
    for (int k = s + tid; k < e; k += 256) {
        uint2 el = tmp[k];
        int lr = (el.x >> 16) & 255;
        int rank = atomicAdd(&rcnt[lr], 1);
        cv[s + rstart[lr] + rank] =
            (f2h_bits(__uint_as_float(el.y)) << 16) | (el.x & 0xffffu);
    }
}

// ---------------- transpose: x (B,T,IN) -> X2h (IN, 256) fp16, col = t*8+b ----------------

__global__ void transpose_x2(const float* __restrict__ x, _Float16* __restrict__ X2h) {
    extern __shared__ float tile[];   // 64 * 257 floats
    int i0 = blockIdx.x * 64;
    int tid = threadIdx.x;
    int il = tid & 63, tg = tid >> 6;
    for (int k = 0; k < 64; ++k) {
        int tb = k * 4 + tg;                 // 0..255
        int t = tb >> 3, b = tb & 7;
        int i = i0 + il;
        float v = (i < INSZ) ? x[((size_t)b * TSZ + t) * INSZ + i] : 0.f;
        tile[il * 257 + tb] = v;             // stride 257: conflict-free
    }
    __syncthreads();
    for (int k = 0; k < 64; ++k) {
        int i = i0 + k;
        if (i < INSZ) X2h[(size_t)i * 256 + tid] = (_Float16)tile[k * 257 + tid];
    }
}

// ---------------- ihc: one wave per row; output t-major via LDS transpose ----------------

__global__ void ihc_kernel(const int* __restrict__ ptr, const unsigned* __restrict__ cv,
                           const float* __restrict__ bias, const half4* __restrict__ X2h,
                           half4* __restrict__ ihcT) {
    __shared__ half4 lds[4 * 65];
    int wid = threadIdx.x >> 6;
    int lane = threadIdx.x & 63;
    int r = (blockIdx.x << 2) + wid;          // HSZ % 4 == 0
    int s = ptr[r], e = ptr[r + 1];
    s = __builtin_amdgcn_readfirstlane(s);
    e = __builtin_amdgcn_readfirstlane(e);
    float4 acc = make_float4(0.f, 0.f, 0.f, 0.f);
    int j = s;
    for (; j + 1 < e; j += 2) {
        unsigned a = cv[j], b = cv[j + 1];
        float va = h_bits2f(a >> 16);
        float vb = h_bits2f(b >> 16);
        half4 x0 = X2h[((size_t)(a & 0xffffu) << 6) + lane];
        half4 x1 = X2h[((size_t)(b & 0xffffu) << 6) + lane];
        acc.x = fmaf(va, (float)x0[0], acc.x);
        acc.y = fmaf(va, (float)x0[1], acc.y);
        acc.z = fmaf(va, (float)x0[2], acc.z);
        acc.w = fmaf(va, (float)x0[3], acc.w);
        acc.x = fmaf(vb, (float)x1[0], acc.x);
        acc.y = fmaf(vb, (float)x1[1], acc.y);
        acc.z = fmaf(vb, (float)x1[2], acc.z);
        acc.w = fmaf(vb, (float)x1[3], acc.w);
    }
    if (j < e) {
        unsigned a = cv[j];
        float va = h_bits2f(a >> 16);
        half4 x0 = X2h[((size_t)(a & 0xffffu) << 6) + lane];
        acc.x = fmaf(va, (float)x0[0], acc.x);
        acc.y = fmaf(va, (float)x0[1], acc.y);
        acc.z = fmaf(va, (float)x0[2], acc.z);
        acc.w = fmaf(va, (float)x0[3], acc.w);
    }
    float bb = bias[r];
    half4 o;
    o[0] = (_Float16)(acc.x + bb);
    o[1] = (_Float16)(acc.y + bb);
    o[2] = (_Float16)(acc.z + bb);
    o[3] = (_Float16)(acc.w + bb);
    lds[wid * 65 + lane] = o;
    __syncthreads();
    int plane = threadIdx.x >> 3;
    int w = threadIdx.x & 7;
    int row = w >> 1, q = w & 1;
    int r2 = (blockIdx.x << 2) + row;
    ihcT[((size_t)plane * HSZ + r2) * 2 + q] = lds[row * 65 + 2 * plane + q];
}

// ---------------- recurrence step ----------------

__device__ __forceinline__ float fast_tanh(float x) {
    float e = __expf(2.0f * x);
    return 1.0f - __fdividef(2.0f, e + 1.0f);
}

__global__ void step_kernel(const int* __restrict__ ptr, const unsigned* __restrict__ cv,
                            const half8* __restrict__ ihcT, const half8* __restrict__ h_in,
                            half8* __restrict__ h_out, float* __restrict__ out, int t) {
    int gid = blockIdx.x * 256 + threadIdx.x;    // gid = r*4 + sub
    if (gid >= 4 * HSZ) return;
    int sub = gid & 3;
    int r = gid >> 2;
    int s = ptr[r], e = ptr[r + 1];
    half8 base8 = ihcT[(size_t)t * HSZ + r];
    float acc0 = 0.f, acc1 = 0.f, acc2 = 0.f, acc3 = 0.f;
    float acc4 = 0.f, acc5 = 0.f, acc6 = 0.f, acc7 = 0.f;
    for (int j = s + sub; j < e; j += 4) {
        unsigned u = cv[j];
        float v = h_bits2f(u >> 16);
        half8 hv = h_in[u & 0xffffu];
        acc0 = fmaf(v, (float)hv[0], acc0);
        acc1 = fmaf(v, (float)hv[1], acc1);
        acc2 = fmaf(v, (float)hv[2], acc2);
        acc3 = fmaf(v, (float)hv[3], acc3);
        acc4 = fmaf(v, (float)hv[4], acc4);
        acc5 = fmaf(v, (float)hv[5], acc5);
        acc6 = fmaf(v, (float)hv[6], acc6);
        acc7 = fmaf(v, (float)hv[7], acc7);
    }
    acc0 += __shfl_xor(acc0, 1); acc1 += __shfl_xor(acc1, 1);
    acc2 += __shfl_xor(acc2, 1); acc3 += __shfl_xor(acc3, 1);
    acc4 += __shfl_xor(acc4, 1); acc5 += __shfl_xor(acc5, 1);
    acc6 += __shfl_xor(acc6, 1); acc7 += __shfl_xor(acc7, 1);
    acc0 += __shfl_xor(acc0, 2); acc1 += __shfl_xor(acc1, 2);
    acc2 += __shfl_xor(acc2, 2); acc3 += __shfl_xor(acc3, 2);
    acc4 += __shfl_xor(acc4, 2); acc5 += __shfl_xor(acc5, 2);
    acc6 += __shfl_xor(acc6, 2); acc7 += __shfl_xor(acc7, 2);
    if (sub == 0) {
        float h0 = fast_tanh(acc0 + (float)base8[0]);
        float h1 = fast_tanh(acc1 + (float)base8[1]);
        float h2 = fast_tanh(acc2 + (float)base8[2]);
        float h3 = fast_tanh(acc3 + (float)base8[3]);
        float h4 = fast_tanh(acc4 + (float)base8[4]);
        float h5 = fast_tanh(acc5 + (float)base8[5]);
        float h6 = fast_tanh(acc6 + (float)base8[6]);
        float h7 = fast_tanh(acc7 + (float)base8[7]);
        half8 hh;
        hh[0] = (_Float16)h0; hh[1] = (_Float16)h1;
        hh[2] = (_Float16)h2; hh[3] = (_Float16)h3;
        hh[4] = (_Float16)h4; hh[5] = (_Float16)h5;
        hh[6] = (_Float16)h6; hh[7] = (_Float16)h7;
        h_out[r] = hh;
        out[((size_t)0 * TSZ + t) * HSZ + r] = h0;
        out[((size_t)1 * TSZ + t) * HSZ + r] = h1;
        out[((size_t)2 * TSZ + t) * HSZ + r] = h2;
        out[((size_t)3 * TSZ + t) * HSZ + r] = h3;
        out[((size_t)4 * TSZ + t) * HSZ + r] = h4;
        out[((size_t)5 * TSZ + t) * HSZ + r] = h5;
        out[((size_t)6 * TSZ + t) * HSZ + r] = h6;
        out[((size_t)7 * TSZ + t) * HSZ + r] = h7;
    }
}

// ---------------- launch ----------------

static inline size_t align256(size_t x) { return (x + 255) & ~(size_t)255; }

extern "C" void kernel_launch(void* const* d_in, const int* in_sizes, int n_in,
                              void* d_out, int out_size, void* d_ws, size_t ws_size,
                              hipStream_t stream) {
    const float* x          = (const float*)d_in[0];
    const float* hh_values  = (const float*)d_in[1];
    const float* hh_bias    = (const float*)d_in[2];
    const float* ih_values  = (const float*)d_in[3];
    const int*   hh_indices = (const int*)d_in[4];
    const int*   ih_indices = (const int*)d_in[5];
    float* out = (float*)d_out;

    char* ws = (char*)d_ws;
    _Float16* X2h   = (_Float16*)ws; ws += align256((size_t)INSZ * 256 * 2);   // 25.6 MB
    half4*  ihcT    = (half4*)ws;  ws += align256((size_t)HSZ * 256 * 2);      // 25.6 MB
    half8*  hbuf    = (half8*)ws;  ws += align256((size_t)2 * HSZ * 16);       // 1.6 MB
    int*    hh_ptr  = (int*)ws;    ws += align256((size_t)(HSZ + 1) * 4);
    int*    ih_ptr  = (int*)ws;    ws += align256((size_t)(HSZ + 1) * 4);
    int*    ghist   = (int*)ws;    ws += align256((size_t)2 * HWORDS * 4);     // 800 KB
    int*    partials= (int*)ws;    ws += align256((size_t)256 * 4);
    int*    cbs     = (int*)ws;    ws += align256((size_t)2 * (NCB + 1) * 4);
    uint2*  tmp_hh  = (uint2*)ws;  ws += align256((size_t)NNZc * 8);           // 6.4 MB
    uint2*  tmp_ih  = (uint2*)ws;  ws += align256((size_t)NNZc * 8);           // 6.4 MB
    unsigned* cv_hh = (unsigned*)ws; ws += align256((size_t)NNZc * 4);         // 3.2 MB
    unsigned* cv_ih = (unsigned*)ws; ws += align256((size_t)NNZc * 4);         // 3.2 MB

    hipMemsetAsync(hbuf, 0, (size_t)HSZ * 16, stream);   // h0 = 0

    p1_count<<<dim3(NBLK, 2), 256, 0, stream>>>(hh_indices, ih_indices, ghist);
    p2scanA<<<dim3(NC2, 2), 1024, 0, stream>>>(ghist, partials);
    p2scanB<<<1, 128, 0, stream>>>(partials);
    p2scanC<<<dim3((HWORDS + 255) / 256, 2), 256, 0, stream>>>(ghist, partials, cbs);
    p2_part<<<dim3(NBLK, 2), 256, 0, stream>>>(hh_indices, hh_values, ih_indices, ih_values,
                                               ghist, tmp_hh, tmp_ih);
    p3_final<<<dim3(NCB, 2), 256, 0, stream>>>(cbs, tmp_hh, tmp_ih,
                                               hh_ptr, ih_ptr, cv_hh, cv_ih);

    transpose_x2<<<(INSZ + 63) / 64, 256, 64 * 257 * 4, stream>>>(x, X2h);
    ihc_kernel<<<HSZ / 4, 256, 0, stream>>>(ih_ptr, cv_ih, hh_bias, (const half4*)X2h, ihcT);

    int stepBlocks = (4 * HSZ + 255) / 256;
    for (int t = 0; t < TSZ; ++t) {
        half8* hin  = hbuf + (size_t)(t & 1) * HSZ;
        half8* hout = hbuf + (size_t)((t + 1) & 1) * HSZ;
        step_kernel<<<stepBlocks, 256, 0, stream>>>(hh_ptr, cv_hh, (const half8*)ihcT,
                                                    hin, hout, out, t);
    }
}